// Round 3
// baseline (583.350 us; speedup 1.0000x reference)
//
#include <hip/hip_runtime.h>
#include <hip/hip_bf16.h>

#define B 16
#define L 128
#define H 256
#define H2 512
#define P 16
#define EPSF 1e-8f

// ---- K1: plain norms of q1/q2 fw & bw halves -------------------------------
__global__ void k_norms(const float* __restrict__ q1, const float* __restrict__ q2,
                        float* n1f, float* n1b, float* n2f, float* n2b) {
    int blk = blockIdx.x;          // b*L + i
    int t = threadIdx.x;           // 64 threads
    const float* r1 = q1 + (size_t)blk * H2;
    const float* r2 = q2 + (size_t)blk * H2;
    int h = t * 4;                 // 64*4 = 256 = H
    float4 a = *(const float4*)(r1 + h);
    float4 bb = *(const float4*)(r1 + H + h);
    float4 c = *(const float4*)(r2 + h);
    float4 d = *(const float4*)(r2 + H + h);
    float s1f = a.x * a.x + a.y * a.y + a.z * a.z + a.w * a.w;
    float s1b = bb.x * bb.x + bb.y * bb.y + bb.z * bb.z + bb.w * bb.w;
    float s2f = c.x * c.x + c.y * c.y + c.z * c.z + c.w * c.w;
    float s2b = d.x * d.x + d.y * d.y + d.z * d.z + d.w * d.w;
    for (int off = 32; off; off >>= 1) {
        s1f += __shfl_down(s1f, off);
        s1b += __shfl_down(s1b, off);
        s2f += __shfl_down(s2f, off);
        s2b += __shfl_down(s2b, off);
    }
    if (t == 0) {
        n1f[blk] = sqrtf(s1f); n1b[blk] = sqrtf(s1b);
        n2f[blk] = sqrtf(s2f); n2b[blk] = sqrtf(s2b);
    }
}

// ---- K2: cosine attention matrices att_fw/att_bw ---------------------------
__global__ void __launch_bounds__(128) k_att(
        const float* __restrict__ q1, const float* __restrict__ q2,
        const float* __restrict__ n1f, const float* __restrict__ n1b,
        const float* __restrict__ n2f, const float* __restrict__ n2b,
        float* __restrict__ att_fw, float* __restrict__ att_bw) {
    int blk = blockIdx.x;          // b*L + i
    int b = blk / L;
    int j = threadIdx.x;           // 128 threads
    __shared__ float a_f[H], a_b[H];
    const float* r1 = q1 + (size_t)blk * H2;
    for (int h = j; h < H; h += L) {
        a_f[h] = r1[h];
        a_b[h] = r1[h + H];
    }
    __syncthreads();
    const float* r2 = q2 + ((size_t)b * L + j) * H2;
    float df = 0, db = 0;
    for (int h = 0; h < H; h += 4) {
        float4 vf = *(const float4*)(r2 + h);
        float4 vb = *(const float4*)(r2 + H + h);
        df += a_f[h] * vf.x + a_f[h + 1] * vf.y + a_f[h + 2] * vf.z + a_f[h + 3] * vf.w;
        db += a_b[h] * vb.x + a_b[h + 1] * vb.y + a_b[h + 2] * vb.z + a_b[h + 3] * vb.w;
    }
    float denf = n1f[blk] * n2f[b * L + j];
    float denb = n1b[blk] * n2b[b * L + j];
    denf = denf > EPSF ? denf : EPSF;
    denb = denb > EPSF ? denb : EPSF;
    att_fw[(size_t)blk * L + j] = df / denf;
    att_bw[(size_t)blk * L + j] = db / denb;
}

// ---- K3: attention-weighted mean (bw uses fw row-sum, per reference)
//          and elementwise max over j of att*q2 ------------------------------
__global__ void __launch_bounds__(256) k_meanmax(
        const float* __restrict__ q2,
        const float* __restrict__ att_fw, const float* __restrict__ att_bw,
        float* __restrict__ mean_fw, float* __restrict__ mean_bw,
        float* __restrict__ maxat_fw, float* __restrict__ maxat_bw) {
    int blk = blockIdx.x;          // b*L + i
    int b = blk / L;
    int h = threadIdx.x;           // 256 threads = one per h
    __shared__ float af[L], ab[L];
    if (h < L) {
        af[h] = att_fw[(size_t)blk * L + h];
        ab[h] = att_bw[(size_t)blk * L + h];
    }
    __syncthreads();
    float accf = 0, accb = 0, S = 0;
    float mxf = -INFINITY, mxb = -INFINITY;
    const float* q2b_ = q2 + (size_t)b * L * H2;
    for (int j = 0; j < L; j++) {
        float wf = af[j], wb = ab[j];
        S += wf;                                   // S_fw only (reference bug)
        float cf = q2b_[(size_t)j * H2 + h];
        float cb = q2b_[(size_t)j * H2 + H + h];
        float vf = wf * cf; accf += vf; mxf = fmaxf(mxf, vf);
        float vb = wb * cb; accb += vb; mxb = fmaxf(mxb, vb);
    }
    float Ss = S > EPSF ? S : EPSF;
    size_t o = (size_t)blk * H + h;
    mean_fw[o] = accf / Ss;
    mean_bw[o] = accb / Ss;   // reference divides bw numerator by fw sum
    maxat_fw[o] = mxf;
    maxat_bw[o] = mxb;
}

// ---- K4: six cos_full pieces ------------------------------------------------
__global__ void __launch_bounds__(256) k_cosfull(
        const float* __restrict__ q1, const float* __restrict__ q2,
        const float* __restrict__ mean_fw, const float* __restrict__ mean_bw,
        const float* __restrict__ maxat_fw, const float* __restrict__ maxat_bw,
        const float* __restrict__ W, float* __restrict__ out) {
    int blk = blockIdx.x;          // b*L + i
    int piece = blockIdx.y;        // 0..5
    int b = blk / L;
    int t = threadIdx.x;
    int p = t >> 4, l = t & 15;    // 16 perspectives x 16 lanes

    int widx, col, dir;
    const float* vptr;
    switch (piece) {
        case 0: widx = 0; col = 0;   dir = 0; vptr = q2 + ((size_t)b * L + (L - 1)) * H2;  break;
        case 1: widx = 1; col = 16;  dir = 1; vptr = q2 + ((size_t)b * L) * H2 + H;        break;
        case 2: widx = 4; col = 64;  dir = 0; vptr = mean_fw + (size_t)blk * H;            break;
        case 3: widx = 5; col = 80;  dir = 1; vptr = mean_bw + (size_t)blk * H;            break;
        case 4: widx = 6; col = 96;  dir = 0; vptr = maxat_fw + (size_t)blk * H;           break;
        default: widx = 7; col = 112; dir = 1; vptr = maxat_bw + (size_t)blk * H;          break;
    }
    const float* r1 = q1 + (size_t)blk * H2 + dir * H;
    const float* wrow = W + ((size_t)widx * P + p) * H;
    float num = 0, na = 0, nc = 0;
    for (int k = 0; k < 16; k++) {
        int h = l + 16 * k;
        float wv = wrow[h];
        float ws = wv * wv;
        float a = r1[h];
        float c = vptr[h];
        num += a * c * ws;
        na  += a * a * ws;
        nc  += c * c * ws;
    }
    for (int off = 8; off; off >>= 1) {
        num += __shfl_down(num, off, 16);
        na  += __shfl_down(na,  off, 16);
        nc  += __shfl_down(nc,  off, 16);
    }
    if (l == 0) {
        float den = sqrtf(na) * sqrtf(nc);
        den = den > EPSF ? den : EPSF;
        out[(size_t)blk * 128 + col + p] = num / den;
    }
}

// ---- K5: cos_maxpool (dominant FLOPs) --------------------------------------
// One block per (b, dir, p). 256 threads: j = t&127, half = t>>7 (two i's/iter).
__global__ void __launch_bounds__(256) k_maxpool(
        const float* __restrict__ q1, const float* __restrict__ q2,
        const float* __restrict__ W, float* __restrict__ out) {
    int b = blockIdx.x, dir = blockIdx.y, p = blockIdx.z;
    int t = threadIdx.x;
    int j = t & 127, half = t >> 7;
    __shared__ float wsq[H];
    __shared__ float na[L], nc[L];
    __shared__ float av[2][H];
    __shared__ float red[4];

    const float* wrow = W + ((size_t)(2 + dir) * P + p) * H;
    wsq[t] = wrow[t] * wrow[t];               // 256 threads cover H=256
    __syncthreads();

    // weighted NORMS (sqrt!): half0 -> na over q1 rows, half1 -> nc over q2 rows
    {
        const float* row = (half == 0 ? q1 : q2) + ((size_t)b * L + j) * H2 + dir * H;
        float s = 0;
        for (int h = 0; h < H; h += 4) {
            float4 v = *(const float4*)(row + h);
            s += v.x * v.x * wsq[h] + v.y * v.y * wsq[h + 1]
               + v.z * v.z * wsq[h + 2] + v.w * v.w * wsq[h + 3];
        }
        if (half == 0) na[j] = sqrtf(s); else nc[j] = sqrtf(s);
    }
    __syncthreads();

    const float* q1base = q1 + (size_t)b * L * H2 + dir * H;
    const float* q2base = q2 + (size_t)b * L * H2 + dir * H;
    const float* r2 = q2base + (size_t)j * H2;

    for (int i0 = 0; i0 < L; i0 += 2) {
        int i = i0 + half;
        const float* r1 = q1base + (size_t)i * H2;
        av[half][j]       = r1[j]       * wsq[j];
        av[half][j + 128] = r1[j + 128] * wsq[j + 128];
        __syncthreads();

        const float* a = av[half];
        float acc = 0;
        for (int h = 0; h < H; h += 4) {
            float4 v = *(const float4*)(r2 + h);
            acc += a[h] * v.x + a[h + 1] * v.y + a[h + 2] * v.z + a[h + 3] * v.w;
        }
        float den = na[i] * nc[j];
        den = den > EPSF ? den : EPSF;
        float val = acc / den;

        for (int off = 32; off; off >>= 1) val = fmaxf(val, __shfl_down(val, off));
        if ((t & 63) == 0) red[t >> 6] = val;
        __syncthreads();
        if (t == 0)
            out[((size_t)b * L + i0) * 128 + 32 + dir * 16 + p] =
                fmaxf(red[0], red[1]);
        else if (t == 128)
            out[((size_t)b * L + i0 + 1) * 128 + 32 + dir * 16 + p] =
                fmaxf(red[2], red[3]);
        __syncthreads();
    }
}

extern "C" void kernel_launch(void* const* d_in, const int* in_sizes, int n_in,
                              void* d_out, int out_size, void* d_ws, size_t ws_size,
                              hipStream_t stream) {
    const float* q1 = (const float*)d_in[0];
    const float* q2 = (const float*)d_in[1];
    const float* W  = (const float*)d_in[2];
    float* out = (float*)d_out;

    float* ws = (float*)d_ws;
    float* n1f = ws;
    float* n1b = n1f + B * L;
    float* n2f = n1b + B * L;
    float* n2b = n2f + B * L;
    float* att_fw = n2b + B * L;              // B*L*L
    float* att_bw = att_fw + (size_t)B * L * L;
    float* mean_fw = att_bw + (size_t)B * L * L;   // B*L*H each below
    float* mean_bw = mean_fw + (size_t)B * L * H;
    float* maxat_fw = mean_bw + (size_t)B * L * H;
    float* maxat_bw = maxat_fw + (size_t)B * L * H;

    k_norms<<<B * L, 64, 0, stream>>>(q1, q2, n1f, n1b, n2f, n2b);
    k_att<<<B * L, 128, 0, stream>>>(q1, q2, n1f, n1b, n2f, n2b, att_fw, att_bw);
    k_meanmax<<<B * L, 256, 0, stream>>>(q2, att_fw, att_bw, mean_fw, mean_bw,
                                         maxat_fw, maxat_bw);
    k_cosfull<<<dim3(B * L, 6), 256, 0, stream>>>(q1, q2, mean_fw, mean_bw,
                                                  maxat_fw, maxat_bw, W, out);
    k_maxpool<<<dim3(B, 2, P), 256, 0, stream>>>(q1, q2, W, out);
}

// Round 4
// 199.167 us; speedup vs baseline: 2.9290x; 2.9290x over previous
//
#include <hip/hip_runtime.h>
#include <hip/hip_bf16.h>

#define B 16
#define L 128
#define H 256
#define H2 512
#define P 16
#define EPSF 1e-8f
#define LDSTR 72   // shorts per LDS row: 64 + 8 pad -> 144 B (9x16B, 2-way bank alias = free)

typedef __attribute__((ext_vector_type(8))) short short8;
typedef __attribute__((ext_vector_type(4))) short short4v;
typedef __attribute__((ext_vector_type(4))) float f32x4;

__device__ __forceinline__ short f2bf(float x) {
    unsigned u = __builtin_bit_cast(unsigned, x);
    u += 0x7fffu + ((u >> 16) & 1u);   // RNE; inputs finite
    return (short)(u >> 16);
}
__device__ __forceinline__ float bf2f(short s) {
    unsigned u = ((unsigned)(unsigned short)s) << 16;
    return __builtin_bit_cast(float, u);
}

// ---- K1: plain norms of q1/q2 fw & bw halves -------------------------------
__global__ void k_norms(const float* __restrict__ q1, const float* __restrict__ q2,
                        float* n1f, float* n1b, float* n2f, float* n2b) {
    int blk = blockIdx.x;          // b*L + i
    int t = threadIdx.x;           // 64 threads
    const float* r1 = q1 + (size_t)blk * H2;
    const float* r2 = q2 + (size_t)blk * H2;
    int h = t * 4;                 // 64*4 = 256 = H
    float4 a = *(const float4*)(r1 + h);
    float4 bb = *(const float4*)(r1 + H + h);
    float4 c = *(const float4*)(r2 + h);
    float4 d = *(const float4*)(r2 + H + h);
    float s1f = a.x * a.x + a.y * a.y + a.z * a.z + a.w * a.w;
    float s1b = bb.x * bb.x + bb.y * bb.y + bb.z * bb.z + bb.w * bb.w;
    float s2f = c.x * c.x + c.y * c.y + c.z * c.z + c.w * c.w;
    float s2b = d.x * d.x + d.y * d.y + d.z * d.z + d.w * d.w;
    for (int off = 32; off; off >>= 1) {
        s1f += __shfl_down(s1f, off);
        s1b += __shfl_down(s1b, off);
        s2f += __shfl_down(s2f, off);
        s2b += __shfl_down(s2b, off);
    }
    if (t == 0) {
        n1f[blk] = sqrtf(s1f); n1b[blk] = sqrtf(s1b);
        n2f[blk] = sqrtf(s2f); n2b[blk] = sqrtf(s2b);
    }
}

// ---- K2: cosine attention matrices att_fw/att_bw ---------------------------
__global__ void __launch_bounds__(128) k_att(
        const float* __restrict__ q1, const float* __restrict__ q2,
        const float* __restrict__ n1f, const float* __restrict__ n1b,
        const float* __restrict__ n2f, const float* __restrict__ n2b,
        float* __restrict__ att_fw, float* __restrict__ att_bw) {
    int blk = blockIdx.x;          // b*L + i
    int b = blk / L;
    int j = threadIdx.x;           // 128 threads
    __shared__ float a_f[H], a_b[H];
    const float* r1 = q1 + (size_t)blk * H2;
    for (int h = j; h < H; h += L) {
        a_f[h] = r1[h];
        a_b[h] = r1[h + H];
    }
    __syncthreads();
    const float* r2 = q2 + ((size_t)b * L + j) * H2;
    float df = 0, db = 0;
    for (int h = 0; h < H; h += 4) {
        float4 vf = *(const float4*)(r2 + h);
        float4 vb = *(const float4*)(r2 + H + h);
        df += a_f[h] * vf.x + a_f[h + 1] * vf.y + a_f[h + 2] * vf.z + a_f[h + 3] * vf.w;
        db += a_b[h] * vb.x + a_b[h + 1] * vb.y + a_b[h + 2] * vb.z + a_b[h + 3] * vb.w;
    }
    float denf = n1f[blk] * n2f[b * L + j];
    float denb = n1b[blk] * n2b[b * L + j];
    denf = denf > EPSF ? denf : EPSF;
    denb = denb > EPSF ? denb : EPSF;
    att_fw[(size_t)blk * L + j] = df / denf;
    att_bw[(size_t)blk * L + j] = db / denb;
}

// ---- K3: attention-weighted mean (bw uses fw row-sum, per reference)
//          and elementwise max over j of att*q2 ------------------------------
__global__ void __launch_bounds__(256) k_meanmax(
        const float* __restrict__ q2,
        const float* __restrict__ att_fw, const float* __restrict__ att_bw,
        float* __restrict__ mean_fw, float* __restrict__ mean_bw,
        float* __restrict__ maxat_fw, float* __restrict__ maxat_bw) {
    int blk = blockIdx.x;          // b*L + i
    int b = blk / L;
    int h = threadIdx.x;           // 256 threads = one per h
    __shared__ float af[L], ab[L];
    if (h < L) {
        af[h] = att_fw[(size_t)blk * L + h];
        ab[h] = att_bw[(size_t)blk * L + h];
    }
    __syncthreads();
    float accf = 0, accb = 0, S = 0;
    float mxf = -INFINITY, mxb = -INFINITY;
    const float* q2b_ = q2 + (size_t)b * L * H2;
    for (int j = 0; j < L; j++) {
        float wf = af[j], wb = ab[j];
        S += wf;                                   // S_fw only (reference bug)
        float cf = q2b_[(size_t)j * H2 + h];
        float cb = q2b_[(size_t)j * H2 + H + h];
        float vf = wf * cf; accf += vf; mxf = fmaxf(mxf, vf);
        float vb = wb * cb; accb += vb; mxb = fmaxf(mxb, vb);
    }
    float Ss = S > EPSF ? S : EPSF;
    size_t o = (size_t)blk * H + h;
    mean_fw[o] = accf / Ss;
    mean_bw[o] = accb / Ss;   // reference divides bw numerator by fw sum
    maxat_fw[o] = mxf;
    maxat_bw[o] = mxb;
}

// ---- K4: six cos_full pieces ------------------------------------------------
__global__ void __launch_bounds__(256) k_cosfull(
        const float* __restrict__ q1, const float* __restrict__ q2,
        const float* __restrict__ mean_fw, const float* __restrict__ mean_bw,
        const float* __restrict__ maxat_fw, const float* __restrict__ maxat_bw,
        const float* __restrict__ W, float* __restrict__ out) {
    int blk = blockIdx.x;          // b*L + i
    int piece = blockIdx.y;        // 0..5
    int b = blk / L;
    int t = threadIdx.x;
    int p = t >> 4, l = t & 15;    // 16 perspectives x 16 lanes

    int widx, col, dir;
    const float* vptr;
    switch (piece) {
        case 0: widx = 0; col = 0;   dir = 0; vptr = q2 + ((size_t)b * L + (L - 1)) * H2;  break;
        case 1: widx = 1; col = 16;  dir = 1; vptr = q2 + ((size_t)b * L) * H2 + H;        break;
        case 2: widx = 4; col = 64;  dir = 0; vptr = mean_fw + (size_t)blk * H;            break;
        case 3: widx = 5; col = 80;  dir = 1; vptr = mean_bw + (size_t)blk * H;            break;
        case 4: widx = 6; col = 96;  dir = 0; vptr = maxat_fw + (size_t)blk * H;           break;
        default: widx = 7; col = 112; dir = 1; vptr = maxat_bw + (size_t)blk * H;          break;
    }
    const float* r1 = q1 + (size_t)blk * H2 + dir * H;
    const float* wrow = W + ((size_t)widx * P + p) * H;
    float num = 0, na = 0, nc = 0;
    for (int k = 0; k < 16; k++) {
        int h = l + 16 * k;
        float wv = wrow[h];
        float ws = wv * wv;
        float a = r1[h];
        float c = vptr[h];
        num += a * c * ws;
        na  += a * a * ws;
        nc  += c * c * ws;
    }
    for (int off = 8; off; off >>= 1) {
        num += __shfl_down(num, off, 16);
        na  += __shfl_down(na,  off, 16);
        nc  += __shfl_down(nc,  off, 16);
    }
    if (l == 0) {
        float den = sqrtf(na) * sqrtf(nc);
        den = den > EPSF ? den : EPSF;
        out[(size_t)blk * 128 + col + p] = num / den;
    }
}

// ---- K5: cos_maxpool via bf16 MFMA ------------------------------------------
// Block per (b*2+dir, p): 512 blocks x 256 thr (4 waves). Each wave computes a
// 32x128 strip of C = (q1*w)(q2*w)^T over K=256 (staged in LDS as bf16, 64-col
// chunks). Norms accumulated from the staged bf16 (self-consistent with num).
__global__ void __launch_bounds__(256, 2) k_maxpool_mfma(
        const float* __restrict__ q1, const float* __restrict__ q2,
        const float* __restrict__ W, float* __restrict__ out) {
    int bd = blockIdx.x;          // b*2 + dir
    int b = bd >> 1, dir = bd & 1;
    int p = blockIdx.y;
    int t = threadIdx.x;

    __shared__ short As[128 * LDSTR];
    __shared__ short Bs[128 * LDSTR];
    __shared__ float wv[H];
    __shared__ float nrm[256];    // [0..127]=||a_i||, [128..255]=||c_j||

    wv[t] = W[((size_t)(2 + dir) * P + p) * H + t];
    __syncthreads();

    f32x4 acc[2][8];
    for (int mt = 0; mt < 2; mt++)
        for (int nt = 0; nt < 8; nt++)
            acc[mt][nt] = (f32x4){0.f, 0.f, 0.f, 0.f};

    int lane16 = t & 15;
    int rgrp = t >> 4;            // 0..15 (staging row group)
    int nrow = t & 127;           // norm row
    int nmat = t >> 7;            // 0 = A, 1 = B
    float normacc = 0.f;

    int wave = t >> 6;
    int l = t & 63;
    int q = l >> 4;
    int coll = l & 15;
    int m0 = wave * 32;

    const float* q1b = q1 + ((size_t)b * L) * H2 + dir * H;
    const float* q2b = q2 + ((size_t)b * L) * H2 + dir * H;

    for (int kt = 0; kt < 4; kt++) {
        int k0 = kt * 64;
        // stage A = q1*w, B = q2*w as bf16, 128 rows x 64 cols
        for (int pass = 0; pass < 8; pass++) {
            int row = rgrp + pass * 16;
            int c4 = lane16 * 4;
            float w0 = wv[k0 + c4], w1 = wv[k0 + c4 + 1];
            float w2 = wv[k0 + c4 + 2], w3 = wv[k0 + c4 + 3];
            float4 va = *(const float4*)(q1b + (size_t)row * H2 + k0 + c4);
            short4v sa = { f2bf(va.x * w0), f2bf(va.y * w1), f2bf(va.z * w2), f2bf(va.w * w3) };
            *(short4v*)(As + row * LDSTR + c4) = sa;
            float4 vb = *(const float4*)(q2b + (size_t)row * H2 + k0 + c4);
            short4v sb = { f2bf(vb.x * w0), f2bf(vb.y * w1), f2bf(vb.z * w2), f2bf(vb.w * w3) };
            *(short4v*)(Bs + row * LDSTR + c4) = sb;
        }
        __syncthreads();
        // norm accumulation from the staged bf16 chunk
        {
            const short* rowp = (nmat ? Bs : As) + nrow * LDSTR;
            for (int c = 0; c < 8; c++) {
                short8 s = *(const short8*)(rowp + c * 8);
                for (int jj = 0; jj < 8; jj++) {
                    float f = bf2f(s[jj]);
                    normacc += f * f;
                }
            }
        }
        // MFMA over this K-chunk (two K=32 sub-steps)
        for (int ks = 0; ks < 2; ks++) {
            int koff = ks * 32 + q * 8;
            short8 af0 = *(const short8*)(As + (m0 + coll) * LDSTR + koff);
            short8 af1 = *(const short8*)(As + (m0 + 16 + coll) * LDSTR + koff);
            for (int nt = 0; nt < 8; nt++) {
                short8 bfr = *(const short8*)(Bs + (nt * 16 + coll) * LDSTR + koff);
                acc[0][nt] = __builtin_amdgcn_mfma_f32_16x16x32_bf16(af0, bfr, acc[0][nt], 0, 0, 0);
                acc[1][nt] = __builtin_amdgcn_mfma_f32_16x16x32_bf16(af1, bfr, acc[1][nt], 0, 0, 0);
            }
        }
        __syncthreads();
    }
    nrm[t] = sqrtf(normacc);
    __syncthreads();

    // epilogue: val = num / max(na*nc, EPS); max over j (cols)
    float nav[2][4];
    for (int mt = 0; mt < 2; mt++)
        for (int r = 0; r < 4; r++)
            nav[mt][r] = nrm[m0 + mt * 16 + q * 4 + r];
    float rmax[2][4];
    for (int mt = 0; mt < 2; mt++)
        for (int r = 0; r < 4; r++) rmax[mt][r] = -INFINITY;
    for (int nt = 0; nt < 8; nt++) {
        float ncv = nrm[128 + nt * 16 + coll];
        for (int mt = 0; mt < 2; mt++)
            for (int r = 0; r < 4; r++) {
                float den = fmaxf(nav[mt][r] * ncv, EPSF);
                float v = acc[mt][nt][r] / den;
                rmax[mt][r] = fmaxf(rmax[mt][r], v);
            }
    }
    for (int off = 1; off < 16; off <<= 1)
        for (int mt = 0; mt < 2; mt++)
            for (int r = 0; r < 4; r++)
                rmax[mt][r] = fmaxf(rmax[mt][r], __shfl_xor(rmax[mt][r], off, 16));
    if (coll == 0) {
        for (int mt = 0; mt < 2; mt++)
            for (int r = 0; r < 4; r++) {
                int row = m0 + mt * 16 + q * 4 + r;
                out[((size_t)b * L + row) * 128 + 32 + dir * 16 + p] = rmax[mt][r];
            }
    }
}

extern "C" void kernel_launch(void* const* d_in, const int* in_sizes, int n_in,
                              void* d_out, int out_size, void* d_ws, size_t ws_size,
                              hipStream_t stream) {
    const float* q1 = (const float*)d_in[0];
    const float* q2 = (const float*)d_in[1];
    const float* W  = (const float*)d_in[2];
    float* out = (float*)d_out;

    float* ws = (float*)d_ws;
    float* n1f = ws;
    float* n1b = n1f + B * L;
    float* n2f = n1b + B * L;
    float* n2b = n2f + B * L;
    float* att_fw = n2b + B * L;              // B*L*L
    float* att_bw = att_fw + (size_t)B * L * L;
    float* mean_fw = att_bw + (size_t)B * L * L;   // B*L*H each below
    float* mean_bw = mean_fw + (size_t)B * L * H;
    float* maxat_fw = mean_bw + (size_t)B * L * H;
    float* maxat_bw = maxat_fw + (size_t)B * L * H;

    k_norms<<<B * L, 64, 0, stream>>>(q1, q2, n1f, n1b, n2f, n2b);
    k_att<<<B * L, 128, 0, stream>>>(q1, q2, n1f, n1b, n2f, n2b, att_fw, att_bw);
    k_meanmax<<<B * L, 256, 0, stream>>>(q2, att_fw, att_bw, mean_fw, mean_bw,
                                         maxat_fw, maxat_bw);
    k_cosfull<<<dim3(B * L, 6), 256, 0, stream>>>(q1, q2, mean_fw, mean_bw,
                                                  maxat_fw, maxat_bw, W, out);
    k_maxpool_mfma<<<dim3(B * 2, P), 256, 0, stream>>>(q1, q2, W, out);
}

// Round 5
// 181.289 us; speedup vs baseline: 3.2178x; 1.0986x over previous
//
#include <hip/hip_runtime.h>
#include <hip/hip_bf16.h>

#define B 16
#define L 128
#define H 256
#define H2 512
#define P 16
#define EPSF 1e-8f
#define LDSTR 72   // shorts per LDS row: 64 + 8 pad -> 144 B (2-way bank alias = free)

typedef __attribute__((ext_vector_type(8))) short short8;
typedef __attribute__((ext_vector_type(4))) short short4v;
typedef __attribute__((ext_vector_type(4))) float f32x4;

__device__ __forceinline__ short f2bf(float x) {
    unsigned u = __builtin_bit_cast(unsigned, x);
    u += 0x7fffu + ((u >> 16) & 1u);   // RNE; inputs finite
    return (short)(u >> 16);
}
__device__ __forceinline__ float bf2f(short s) {
    unsigned u = ((unsigned)(unsigned short)s) << 16;
    return __builtin_bit_cast(float, u);
}

// ---- K1: attention via bf16 MFMA + exact fp32 norms ------------------------
// Block per (b*2+dir): 32 blocks x 256 thr (4 waves). Computes
// att = (q1h.q2h^T) / max(|q1h_i||q2h_j|, EPS) in fp32, plus fw row sums.
__global__ void __launch_bounds__(256, 2) k_att_mfma(
        const float* __restrict__ q1, const float* __restrict__ q2,
        float* __restrict__ att_fw, float* __restrict__ att_bw,
        float* __restrict__ attsum) {
    int bd = blockIdx.x;
    int b = bd >> 1, dir = bd & 1;
    int t = threadIdx.x;

    __shared__ short As[128 * LDSTR];
    __shared__ short Bs[128 * LDSTR];
    __shared__ float nA[L], nB[L];

    f32x4 acc[2][8];
    for (int mt = 0; mt < 2; mt++)
        for (int nt = 0; nt < 8; nt++)
            acc[mt][nt] = (f32x4){0.f, 0.f, 0.f, 0.f};

    int lane16 = t & 15;
    int rgrp = t >> 4;            // 0..15
    int wave = t >> 6;
    int l = t & 63;
    int q = l >> 4;
    int coll = l & 15;
    int m0 = wave * 32;

    const float* q1b = q1 + ((size_t)b * L) * H2 + dir * H;
    const float* q2b = q2 + ((size_t)b * L) * H2 + dir * H;

    float normA[8], normB[8];
    for (int pp = 0; pp < 8; pp++) { normA[pp] = 0.f; normB[pp] = 0.f; }

    for (int kt = 0; kt < 4; kt++) {
        int k0 = kt * 64;
        for (int pass = 0; pass < 8; pass++) {
            int row = rgrp + pass * 16;
            int c4 = lane16 * 4;
            float4 va = *(const float4*)(q1b + (size_t)row * H2 + k0 + c4);
            normA[pass] += va.x * va.x + va.y * va.y + va.z * va.z + va.w * va.w;
            short4v sa = { f2bf(va.x), f2bf(va.y), f2bf(va.z), f2bf(va.w) };
            *(short4v*)(As + row * LDSTR + c4) = sa;
            float4 vb = *(const float4*)(q2b + (size_t)row * H2 + k0 + c4);
            normB[pass] += vb.x * vb.x + vb.y * vb.y + vb.z * vb.z + vb.w * vb.w;
            short4v sb = { f2bf(vb.x), f2bf(vb.y), f2bf(vb.z), f2bf(vb.w) };
            *(short4v*)(Bs + row * LDSTR + c4) = sb;
        }
        __syncthreads();
        for (int ks = 0; ks < 2; ks++) {
            int koff = ks * 32 + q * 8;
            short8 af0 = *(const short8*)(As + (m0 + coll) * LDSTR + koff);
            short8 af1 = *(const short8*)(As + (m0 + 16 + coll) * LDSTR + koff);
            for (int nt = 0; nt < 8; nt++) {
                short8 bfr = *(const short8*)(Bs + (nt * 16 + coll) * LDSTR + koff);
                acc[0][nt] = __builtin_amdgcn_mfma_f32_16x16x32_bf16(af0, bfr, acc[0][nt], 0, 0, 0);
                acc[1][nt] = __builtin_amdgcn_mfma_f32_16x16x32_bf16(af1, bfr, acc[1][nt], 0, 0, 0);
            }
        }
        __syncthreads();
    }
    // per-row fp32 norms (exact, from the staged global loads)
    for (int pp = 0; pp < 8; pp++) {
        float sA = normA[pp], sB = normB[pp];
        for (int off = 1; off < 16; off <<= 1) {
            sA += __shfl_xor(sA, off, 16);
            sB += __shfl_xor(sB, off, 16);
        }
        if (lane16 == 0) {
            nA[rgrp + pp * 16] = sqrtf(sA);
            nB[rgrp + pp * 16] = sqrtf(sB);
        }
    }
    __syncthreads();

    float* attout = dir ? att_bw : att_fw;
    float n1v[2][4];
    for (int mt = 0; mt < 2; mt++)
        for (int r = 0; r < 4; r++)
            n1v[mt][r] = nA[m0 + mt * 16 + q * 4 + r];
    float rsum[2][4];
    for (int mt = 0; mt < 2; mt++)
        for (int r = 0; r < 4; r++) rsum[mt][r] = 0.f;
    size_t bL = (size_t)b * L;
    for (int nt = 0; nt < 8; nt++) {
        float n2v = nB[nt * 16 + coll];
        for (int mt = 0; mt < 2; mt++)
            for (int r = 0; r < 4; r++) {
                int row = m0 + mt * 16 + q * 4 + r;
                float den = n1v[mt][r] * n2v;
                den = den > EPSF ? den : EPSF;
                float a = acc[mt][nt][r] / den;
                attout[(bL + row) * L + nt * 16 + coll] = a;
                rsum[mt][r] += a;
            }
    }
    if (dir == 0) {
        for (int off = 1; off < 16; off <<= 1)
            for (int mt = 0; mt < 2; mt++)
                for (int r = 0; r < 4; r++)
                    rsum[mt][r] += __shfl_xor(rsum[mt][r], off, 16);
        if (coll == 0)
            for (int mt = 0; mt < 2; mt++)
                for (int r = 0; r < 4; r++)
                    attsum[bL + m0 + mt * 16 + q * 4 + r] = rsum[mt][r];
    }
}

// ---- K2: weighted mean (bw uses fw row-sum, per reference) + max of att*q2 --
// Block per (b, i-group of 8): 256 blocks x 256 thr (one per h).
__global__ void __launch_bounds__(256) k_meanmax8(
        const float* __restrict__ q2,
        const float* __restrict__ att_fw, const float* __restrict__ att_bw,
        const float* __restrict__ attsum,
        float* __restrict__ mean_fw, float* __restrict__ mean_bw,
        float* __restrict__ maxat_fw, float* __restrict__ maxat_bw) {
    int b = blockIdx.x >> 4;
    int i0 = (blockIdx.x & 15) * 8;
    int h = threadIdx.x;
    __shared__ float af[8][L], ab[8][L], Ss[8];
    for (int v = h; v < 8 * L; v += 256) {
        int r = v >> 7, j = v & 127;
        af[r][j] = att_fw[((size_t)b * L + i0 + r) * L + j];
        ab[r][j] = att_bw[((size_t)b * L + i0 + r) * L + j];
    }
    if (h < 8) {
        float s = attsum[(size_t)b * L + i0 + h];
        Ss[h] = s > EPSF ? s : EPSF;
    }
    __syncthreads();
    float accf[8], accb[8], mxf[8], mxb[8];
    for (int r = 0; r < 8; r++) {
        accf[r] = 0.f; accb[r] = 0.f; mxf[r] = -INFINITY; mxb[r] = -INFINITY;
    }
    const float* q2b_ = q2 + (size_t)b * L * H2;
    for (int j = 0; j < L; j++) {
        float cf = q2b_[(size_t)j * H2 + h];
        float cb = q2b_[(size_t)j * H2 + H + h];
        for (int r = 0; r < 8; r++) {
            float vf = af[r][j] * cf; accf[r] += vf; mxf[r] = fmaxf(mxf[r], vf);
            float vb = ab[r][j] * cb; accb[r] += vb; mxb[r] = fmaxf(mxb[r], vb);
        }
    }
    for (int r = 0; r < 8; r++) {
        size_t o = ((size_t)b * L + i0 + r) * H + h;
        mean_fw[o] = accf[r] / Ss[r];
        mean_bw[o] = accb[r] / Ss[r];   // reference divides bw by fw sum
        maxat_fw[o] = mxf[r];
        maxat_bw[o] = mxb[r];
    }
}

// ---- K3: six cos_full pieces ------------------------------------------------
__global__ void __launch_bounds__(256) k_cosfull(
        const float* __restrict__ q1, const float* __restrict__ q2,
        const float* __restrict__ mean_fw, const float* __restrict__ mean_bw,
        const float* __restrict__ maxat_fw, const float* __restrict__ maxat_bw,
        const float* __restrict__ W, float* __restrict__ out) {
    int blk = blockIdx.x;          // b*L + i
    int piece = blockIdx.y;        // 0..5
    int b = blk / L;
    int t = threadIdx.x;
    int p = t >> 4, l = t & 15;    // 16 perspectives x 16 lanes

    int widx, col, dir;
    const float* vptr;
    switch (piece) {
        case 0: widx = 0; col = 0;   dir = 0; vptr = q2 + ((size_t)b * L + (L - 1)) * H2;  break;
        case 1: widx = 1; col = 16;  dir = 1; vptr = q2 + ((size_t)b * L) * H2 + H;        break;
        case 2: widx = 4; col = 64;  dir = 0; vptr = mean_fw + (size_t)blk * H;            break;
        case 3: widx = 5; col = 80;  dir = 1; vptr = mean_bw + (size_t)blk * H;            break;
        case 4: widx = 6; col = 96;  dir = 0; vptr = maxat_fw + (size_t)blk * H;           break;
        default: widx = 7; col = 112; dir = 1; vptr = maxat_bw + (size_t)blk * H;          break;
    }
    const float* r1 = q1 + (size_t)blk * H2 + dir * H;
    const float* wrow = W + ((size_t)widx * P + p) * H;
    float num = 0, na = 0, nc = 0;
    for (int k = 0; k < 16; k++) {
        int h = l + 16 * k;
        float wv = wrow[h];
        float ws = wv * wv;
        float a = r1[h];
        float c = vptr[h];
        num += a * c * ws;
        na  += a * a * ws;
        nc  += c * c * ws;
    }
    for (int off = 8; off; off >>= 1) {
        num += __shfl_down(num, off, 16);
        na  += __shfl_down(na,  off, 16);
        nc  += __shfl_down(nc,  off, 16);
    }
    if (l == 0) {
        float den = sqrtf(na) * sqrtf(nc);
        den = den > EPSF ? den : EPSF;
        out[(size_t)blk * 128 + col + p] = num / den;
    }
}

// ---- K4: cos_maxpool via bf16 MFMA ------------------------------------------
__global__ void __launch_bounds__(256, 2) k_maxpool_mfma(
        const float* __restrict__ q1, const float* __restrict__ q2,
        const float* __restrict__ W, float* __restrict__ out) {
    int bd = blockIdx.x;          // b*2 + dir
    int b = bd >> 1, dir = bd & 1;
    int p = blockIdx.y;
    int t = threadIdx.x;

    __shared__ short As[128 * LDSTR];
    __shared__ short Bs[128 * LDSTR];
    __shared__ float wv[H];
    __shared__ float nrm[256];    // [0..127]=||a_i||, [128..255]=||c_j||

    wv[t] = W[((size_t)(2 + dir) * P + p) * H + t];
    __syncthreads();

    f32x4 acc[2][8];
    for (int mt = 0; mt < 2; mt++)
        for (int nt = 0; nt < 8; nt++)
            acc[mt][nt] = (f32x4){0.f, 0.f, 0.f, 0.f};

    int lane16 = t & 15;
    int rgrp = t >> 4;
    int nrow = t & 127;
    int nmat = t >> 7;
    float normacc = 0.f;

    int wave = t >> 6;
    int l = t & 63;
    int q = l >> 4;
    int coll = l & 15;
    int m0 = wave * 32;

    const float* q1b = q1 + ((size_t)b * L) * H2 + dir * H;
    const float* q2b = q2 + ((size_t)b * L) * H2 + dir * H;

    for (int kt = 0; kt < 4; kt++) {
        int k0 = kt * 64;
        for (int pass = 0; pass < 8; pass++) {
            int row = rgrp + pass * 16;
            int c4 = lane16 * 4;
            float w0 = wv[k0 + c4], w1 = wv[k0 + c4 + 1];
            float w2 = wv[k0 + c4 + 2], w3 = wv[k0 + c4 + 3];
            float4 va = *(const float4*)(q1b + (size_t)row * H2 + k0 + c4);
            short4v sa = { f2bf(va.x * w0), f2bf(va.y * w1), f2bf(va.z * w2), f2bf(va.w * w3) };
            *(short4v*)(As + row * LDSTR + c4) = sa;
            float4 vb = *(const float4*)(q2b + (size_t)row * H2 + k0 + c4);
            short4v sb = { f2bf(vb.x * w0), f2bf(vb.y * w1), f2bf(vb.z * w2), f2bf(vb.w * w3) };
            *(short4v*)(Bs + row * LDSTR + c4) = sb;
        }
        __syncthreads();
        {
            const short* rowp = (nmat ? Bs : As) + nrow * LDSTR;
            for (int c = 0; c < 8; c++) {
                short8 s = *(const short8*)(rowp + c * 8);
                for (int jj = 0; jj < 8; jj++) {
                    float f = bf2f(s[jj]);
                    normacc += f * f;
                }
            }
        }
        for (int ks = 0; ks < 2; ks++) {
            int koff = ks * 32 + q * 8;
            short8 af0 = *(const short8*)(As + (m0 + coll) * LDSTR + koff);
            short8 af1 = *(const short8*)(As + (m0 + 16 + coll) * LDSTR + koff);
            for (int nt = 0; nt < 8; nt++) {
                short8 bfr = *(const short8*)(Bs + (nt * 16 + coll) * LDSTR + koff);
                acc[0][nt] = __builtin_amdgcn_mfma_f32_16x16x32_bf16(af0, bfr, acc[0][nt], 0, 0, 0);
                acc[1][nt] = __builtin_amdgcn_mfma_f32_16x16x32_bf16(af1, bfr, acc[1][nt], 0, 0, 0);
            }
        }
        __syncthreads();
    }
    nrm[t] = sqrtf(normacc);
    __syncthreads();

    float nav[2][4];
    for (int mt = 0; mt < 2; mt++)
        for (int r = 0; r < 4; r++)
            nav[mt][r] = nrm[m0 + mt * 16 + q * 4 + r];
    float rmax[2][4];
    for (int mt = 0; mt < 2; mt++)
        for (int r = 0; r < 4; r++) rmax[mt][r] = -INFINITY;
    for (int nt = 0; nt < 8; nt++) {
        float ncv = nrm[128 + nt * 16 + coll];
        for (int mt = 0; mt < 2; mt++)
            for (int r = 0; r < 4; r++) {
                float den = fmaxf(nav[mt][r] * ncv, EPSF);
                float v = acc[mt][nt][r] / den;
                rmax[mt][r] = fmaxf(rmax[mt][r], v);
            }
    }
    for (int off = 1; off < 16; off <<= 1)
        for (int mt = 0; mt < 2; mt++)
            for (int r = 0; r < 4; r++)
                rmax[mt][r] = fmaxf(rmax[mt][r], __shfl_xor(rmax[mt][r], off, 16));
    if (coll == 0) {
        for (int mt = 0; mt < 2; mt++)
            for (int r = 0; r < 4; r++) {
                int row = m0 + mt * 16 + q * 4 + r;
                out[((size_t)b * L + row) * 128 + 32 + dir * 16 + p] = rmax[mt][r];
            }
    }
}

extern "C" void kernel_launch(void* const* d_in, const int* in_sizes, int n_in,
                              void* d_out, int out_size, void* d_ws, size_t ws_size,
                              hipStream_t stream) {
    const float* q1 = (const float*)d_in[0];
    const float* q2 = (const float*)d_in[1];
    const float* W  = (const float*)d_in[2];
    float* out = (float*)d_out;

    float* ws = (float*)d_ws;
    float* attsum = ws;                               // B*L
    float* att_fw = attsum + B * L;                   // B*L*L
    float* att_bw = att_fw + (size_t)B * L * L;
    float* mean_fw = att_bw + (size_t)B * L * L;      // B*L*H each below
    float* mean_bw = mean_fw + (size_t)B * L * H;
    float* maxat_fw = mean_bw + (size_t)B * L * H;
    float* maxat_bw = maxat_fw + (size_t)B * L * H;

    k_att_mfma<<<B * 2, 256, 0, stream>>>(q1, q2, att_fw, att_bw, attsum);
    k_meanmax8<<<B * 16, 256, 0, stream>>>(q2, att_fw, att_bw, attsum,
                                           mean_fw, mean_bw, maxat_fw, maxat_bw);
    k_cosfull<<<dim3(B * L, 6), 256, 0, stream>>>(q1, q2, mean_fw, mean_bw,
                                                  maxat_fw, maxat_bw, W, out);
    k_maxpool_mfma<<<dim3(B * 2, P), 256, 0, stream>>>(q1, q2, W, out);
}

// Round 6
// 162.464 us; speedup vs baseline: 3.5906x; 1.1159x over previous
//
#include <hip/hip_runtime.h>
#include <hip/hip_bf16.h>

#define B 16
#define L 128
#define H 256
#define H2 512
#define P 16
#define EPSF 1e-8f
#define LDSTR 72   // shorts per LDS row: 64 + 8 pad -> 144 B (2-way bank alias = free)

typedef __attribute__((ext_vector_type(8))) short short8;
typedef __attribute__((ext_vector_type(4))) short short4v;
typedef __attribute__((ext_vector_type(4))) float f32x4;

__device__ __forceinline__ short f2bf(float x) {
    unsigned u = __builtin_bit_cast(unsigned, x);
    u += 0x7fffu + ((u >> 16) & 1u);   // RNE; inputs finite
    return (short)(u >> 16);
}
__device__ __forceinline__ float bf2f(short s) {
    unsigned u = ((unsigned)(unsigned short)s) << 16;
    return __builtin_bit_cast(float, u);
}

// ---- K1: attention via bf16 MFMA + exact fp32 norms ------------------------
// Grid (B*2, 8): block = 16 q1-rows x 128 q2-cols strip of att for (b,dir).
// 256 thr / 4 waves; wave w covers cols w*32..w*32+31.
__global__ void __launch_bounds__(256) k_att_mfma(
        const float* __restrict__ q1, const float* __restrict__ q2,
        float* __restrict__ att_fw, float* __restrict__ att_bw,
        float* __restrict__ attsum) {
    int bd = blockIdx.x;
    int b = bd >> 1, dir = bd & 1;
    int m0 = blockIdx.y * 16;
    int t = threadIdx.x;

    __shared__ short As[16 * LDSTR];
    __shared__ short Bs[128 * LDSTR];
    __shared__ float nA[16], nB[L];
    __shared__ float part[4][16];

    f32x4 acc[2];
    acc[0] = (f32x4){0.f, 0.f, 0.f, 0.f};
    acc[1] = (f32x4){0.f, 0.f, 0.f, 0.f};

    int wave = t >> 6;
    int l = t & 63;
    int q = l >> 4;
    int coll = l & 15;
    int n0 = wave * 32;

    // staging assignments
    int arow = t >> 4;            // 0..15
    int acol = (t & 15) * 4;
    int brow = t >> 1;            // 0..127
    int bcol0 = (t & 1) * 32;

    const float* q1b = q1 + ((size_t)b * L + m0) * H2 + dir * H;
    const float* q2b = q2 + ((size_t)b * L) * H2 + dir * H;

    float normA = 0.f, normB = 0.f;

    for (int kt = 0; kt < 4; kt++) {
        int k0 = kt * 64;
        // A tile: 16 x 64
        {
            float4 va = *(const float4*)(q1b + (size_t)arow * H2 + k0 + acol);
            normA += va.x * va.x + va.y * va.y + va.z * va.z + va.w * va.w;
            short4v sa = { f2bf(va.x), f2bf(va.y), f2bf(va.z), f2bf(va.w) };
            *(short4v*)(As + arow * LDSTR + acol) = sa;
        }
        // B tile: 128 x 64
        for (int cc = 0; cc < 8; cc++) {
            float4 vb = *(const float4*)(q2b + (size_t)brow * H2 + k0 + bcol0 + cc * 4);
            normB += vb.x * vb.x + vb.y * vb.y + vb.z * vb.z + vb.w * vb.w;
            short4v sb = { f2bf(vb.x), f2bf(vb.y), f2bf(vb.z), f2bf(vb.w) };
            *(short4v*)(Bs + brow * LDSTR + bcol0 + cc * 4) = sb;
        }
        __syncthreads();
        for (int ks = 0; ks < 2; ks++) {
            int koff = ks * 32 + q * 8;
            short8 af = *(const short8*)(As + coll * LDSTR + koff);
            short8 bf0 = *(const short8*)(Bs + (n0 + coll) * LDSTR + koff);
            short8 bf1 = *(const short8*)(Bs + (n0 + 16 + coll) * LDSTR + koff);
            acc[0] = __builtin_amdgcn_mfma_f32_16x16x32_bf16(af, bf0, acc[0], 0, 0, 0);
            acc[1] = __builtin_amdgcn_mfma_f32_16x16x32_bf16(af, bf1, acc[1], 0, 0, 0);
        }
        __syncthreads();
    }
    // exact fp32 norms
    {
        float sA = normA;
        for (int off = 1; off < 16; off <<= 1) sA += __shfl_xor(sA, off, 16);
        if ((t & 15) == 0) nA[arow] = sqrtf(sA);
        float sB = normB + __shfl_xor(normB, 1, 2);
        if ((t & 1) == 0) nB[brow] = sqrtf(sB);
    }
    __syncthreads();

    float* attout = dir ? att_bw : att_fw;
    size_t bL = (size_t)b * L;
    float n1v[4];
    for (int r = 0; r < 4; r++) n1v[r] = nA[q * 4 + r];
    float rsum[4] = {0.f, 0.f, 0.f, 0.f};
    for (int nt = 0; nt < 2; nt++) {
        int col = n0 + nt * 16 + coll;
        float n2v = nB[col];
        for (int r = 0; r < 4; r++) {
            int row = m0 + q * 4 + r;
            float den = n1v[r] * n2v;
            den = den > EPSF ? den : EPSF;
            float a = acc[nt][r] / den;
            attout[(bL + row) * L + col] = a;
            rsum[r] += a;
        }
    }
    if (dir == 0) {
        for (int off = 1; off < 16; off <<= 1)
            for (int r = 0; r < 4; r++)
                rsum[r] += __shfl_xor(rsum[r], off, 16);
        if (coll == 0)
            for (int r = 0; r < 4; r++)
                part[wave][q * 4 + r] = rsum[r];
        __syncthreads();
        if (t < 16)
            attsum[bL + m0 + t] = part[0][t] + part[1][t] + part[2][t] + part[3][t];
    }
}

// ---- K2: weighted mean (bw uses fw row-sum, per reference) + max of att*q2 --
__global__ void __launch_bounds__(256) k_meanmax8(
        const float* __restrict__ q2,
        const float* __restrict__ att_fw, const float* __restrict__ att_bw,
        const float* __restrict__ attsum,
        float* __restrict__ mean_fw, float* __restrict__ mean_bw,
        float* __restrict__ maxat_fw, float* __restrict__ maxat_bw) {
    int b = blockIdx.x >> 4;
    int i0 = (blockIdx.x & 15) * 8;
    int h = threadIdx.x;
    __shared__ float af[8][L], ab[8][L], Ss[8];
    for (int v = h; v < 8 * L; v += 256) {
        int r = v >> 7, j = v & 127;
        af[r][j] = att_fw[((size_t)b * L + i0 + r) * L + j];
        ab[r][j] = att_bw[((size_t)b * L + i0 + r) * L + j];
    }
    if (h < 8) {
        float s = attsum[(size_t)b * L + i0 + h];
        Ss[h] = s > EPSF ? s : EPSF;
    }
    __syncthreads();
    float accf[8], accb[8], mxf[8], mxb[8];
    for (int r = 0; r < 8; r++) {
        accf[r] = 0.f; accb[r] = 0.f; mxf[r] = -INFINITY; mxb[r] = -INFINITY;
    }
    const float* q2b_ = q2 + (size_t)b * L * H2;
    for (int j = 0; j < L; j++) {
        float cf = q2b_[(size_t)j * H2 + h];
        float cb = q2b_[(size_t)j * H2 + H + h];
        for (int r = 0; r < 8; r++) {
            float vf = af[r][j] * cf; accf[r] += vf; mxf[r] = fmaxf(mxf[r], vf);
            float vb = ab[r][j] * cb; accb[r] += vb; mxb[r] = fmaxf(mxb[r], vb);
        }
    }
    for (int r = 0; r < 8; r++) {
        size_t o = ((size_t)b * L + i0 + r) * H + h;
        mean_fw[o] = accf[r] / Ss[r];
        mean_bw[o] = accb[r] / Ss[r];   // reference divides bw by fw sum
        maxat_fw[o] = mxf[r];
        maxat_bw[o] = mxb[r];
    }
}

// ---- K3: six cos_full pieces ------------------------------------------------
__global__ void __launch_bounds__(256) k_cosfull(
        const float* __restrict__ q1, const float* __restrict__ q2,
        const float* __restrict__ mean_fw, const float* __restrict__ mean_bw,
        const float* __restrict__ maxat_fw, const float* __restrict__ maxat_bw,
        const float* __restrict__ W, float* __restrict__ out) {
    int blk = blockIdx.x;          // b*L + i
    int piece = blockIdx.y;        // 0..5
    int b = blk / L;
    int t = threadIdx.x;
    int p = t >> 4, l = t & 15;    // 16 perspectives x 16 lanes

    int widx, col, dir;
    const float* vptr;
    switch (piece) {
        case 0: widx = 0; col = 0;   dir = 0; vptr = q2 + ((size_t)b * L + (L - 1)) * H2;  break;
        case 1: widx = 1; col = 16;  dir = 1; vptr = q2 + ((size_t)b * L) * H2 + H;        break;
        case 2: widx = 4; col = 64;  dir = 0; vptr = mean_fw + (size_t)blk * H;            break;
        case 3: widx = 5; col = 80;  dir = 1; vptr = mean_bw + (size_t)blk * H;            break;
        case 4: widx = 6; col = 96;  dir = 0; vptr = maxat_fw + (size_t)blk * H;           break;
        default: widx = 7; col = 112; dir = 1; vptr = maxat_bw + (size_t)blk * H;          break;
    }
    const float* r1 = q1 + (size_t)blk * H2 + dir * H;
    const float* wrow = W + ((size_t)widx * P + p) * H;
    float num = 0, na = 0, nc = 0;
    for (int k = 0; k < 16; k++) {
        int h = l + 16 * k;
        float wv = wrow[h];
        float ws = wv * wv;
        float a = r1[h];
        float c = vptr[h];
        num += a * c * ws;
        na  += a * a * ws;
        nc  += c * c * ws;
    }
    for (int off = 8; off; off >>= 1) {
        num += __shfl_down(num, off, 16);
        na  += __shfl_down(na,  off, 16);
        nc  += __shfl_down(nc,  off, 16);
    }
    if (l == 0) {
        float den = sqrtf(na) * sqrtf(nc);
        den = den > EPSF ? den : EPSF;
        out[(size_t)blk * 128 + col + p] = num / den;
    }
}

// ---- K4: cos_maxpool via bf16 MFMA ------------------------------------------
__global__ void __launch_bounds__(256, 2) k_maxpool_mfma(
        const float* __restrict__ q1, const float* __restrict__ q2,
        const float* __restrict__ W, float* __restrict__ out) {
    int bd = blockIdx.x;          // b*2 + dir
    int b = bd >> 1, dir = bd & 1;
    int p = blockIdx.y;
    int t = threadIdx.x;

    __shared__ short As[128 * LDSTR];
    __shared__ short Bs[128 * LDSTR];
    __shared__ float wv[H];
    __shared__ float nrm[256];    // [0..127]=||a_i||, [128..255]=||c_j||

    wv[t] = W[((size_t)(2 + dir) * P + p) * H + t];
    __syncthreads();

    f32x4 acc[2][8];
    for (int mt = 0; mt < 2; mt++)
        for (int nt = 0; nt < 8; nt++)
            acc[mt][nt] = (f32x4){0.f, 0.f, 0.f, 0.f};

    int lane16 = t & 15;
    int rgrp = t >> 4;
    int nrow = t & 127;
    int nmat = t >> 7;
    float normacc = 0.f;

    int wave = t >> 6;
    int l = t & 63;
    int q = l >> 4;
    int coll = l & 15;
    int m0 = wave * 32;

    const float* q1b = q1 + ((size_t)b * L) * H2 + dir * H;
    const float* q2b = q2 + ((size_t)b * L) * H2 + dir * H;

    for (int kt = 0; kt < 4; kt++) {
        int k0 = kt * 64;
        for (int pass = 0; pass < 8; pass++) {
            int row = rgrp + pass * 16;
            int c4 = lane16 * 4;
            float w0 = wv[k0 + c4], w1 = wv[k0 + c4 + 1];
            float w2 = wv[k0 + c4 + 2], w3 = wv[k0 + c4 + 3];
            float4 va = *(const float4*)(q1b + (size_t)row * H2 + k0 + c4);
            short4v sa = { f2bf(va.x * w0), f2bf(va.y * w1), f2bf(va.z * w2), f2bf(va.w * w3) };
            *(short4v*)(As + row * LDSTR + c4) = sa;
            float4 vb = *(const float4*)(q2b + (size_t)row * H2 + k0 + c4);
            short4v sb = { f2bf(vb.x * w0), f2bf(vb.y * w1), f2bf(vb.z * w2), f2bf(vb.w * w3) };
            *(short4v*)(Bs + row * LDSTR + c4) = sb;
        }
        __syncthreads();
        {
            const short* rowp = (nmat ? Bs : As) + nrow * LDSTR;
            for (int c = 0; c < 8; c++) {
                short8 s = *(const short8*)(rowp + c * 8);
                for (int jj = 0; jj < 8; jj++) {
                    float f = bf2f(s[jj]);
                    normacc += f * f;
                }
            }
        }
        for (int ks = 0; ks < 2; ks++) {
            int koff = ks * 32 + q * 8;
            short8 af0 = *(const short8*)(As + (m0 + coll) * LDSTR + koff);
            short8 af1 = *(const short8*)(As + (m0 + 16 + coll) * LDSTR + koff);
            for (int nt = 0; nt < 8; nt++) {
                short8 bfr = *(const short8*)(Bs + (nt * 16 + coll) * LDSTR + koff);
                acc[0][nt] = __builtin_amdgcn_mfma_f32_16x16x32_bf16(af0, bfr, acc[0][nt], 0, 0, 0);
                acc[1][nt] = __builtin_amdgcn_mfma_f32_16x16x32_bf16(af1, bfr, acc[1][nt], 0, 0, 0);
            }
        }
        __syncthreads();
    }
    nrm[t] = sqrtf(normacc);
    __syncthreads();

    float nav[2][4];
    for (int mt = 0; mt < 2; mt++)
        for (int r = 0; r < 4; r++)
            nav[mt][r] = nrm[m0 + mt * 16 + q * 4 + r];
    float rmax[2][4];
    for (int mt = 0; mt < 2; mt++)
        for (int r = 0; r < 4; r++) rmax[mt][r] = -INFINITY;
    for (int nt = 0; nt < 8; nt++) {
        float ncv = nrm[128 + nt * 16 + coll];
        for (int mt = 0; mt < 2; mt++)
            for (int r = 0; r < 4; r++) {
                float den = fmaxf(nav[mt][r] * ncv, EPSF);
                float v = acc[mt][nt][r] / den;
                rmax[mt][r] = fmaxf(rmax[mt][r], v);
            }
    }
    for (int off = 1; off < 16; off <<= 1)
        for (int mt = 0; mt < 2; mt++)
            for (int r = 0; r < 4; r++)
                rmax[mt][r] = fmaxf(rmax[mt][r], __shfl_xor(rmax[mt][r], off, 16));
    if (coll == 0) {
        for (int mt = 0; mt < 2; mt++)
            for (int r = 0; r < 4; r++) {
                int row = m0 + mt * 16 + q * 4 + r;
                out[((size_t)b * L + row) * 128 + 32 + dir * 16 + p] = rmax[mt][r];
            }
    }
}

extern "C" void kernel_launch(void* const* d_in, const int* in_sizes, int n_in,
                              void* d_out, int out_size, void* d_ws, size_t ws_size,
                              hipStream_t stream) {
    const float* q1 = (const float*)d_in[0];
    const float* q2 = (const float*)d_in[1];
    const float* W  = (const float*)d_in[2];
    float* out = (float*)d_out;

    float* ws = (float*)d_ws;
    float* attsum = ws;                               // B*L
    float* att_fw = attsum + B * L;                   // B*L*L
    float* att_bw = att_fw + (size_t)B * L * L;
    float* mean_fw = att_bw + (size_t)B * L * L;      // B*L*H each below
    float* mean_bw = mean_fw + (size_t)B * L * H;
    float* maxat_fw = mean_bw + (size_t)B * L * H;
    float* maxat_bw = maxat_fw + (size_t)B * L * H;

    k_att_mfma<<<dim3(B * 2, 8), 256, 0, stream>>>(q1, q2, att_fw, att_bw, attsum);
    k_meanmax8<<<B * 16, 256, 0, stream>>>(q2, att_fw, att_bw, attsum,
                                           mean_fw, mean_bw, maxat_fw, maxat_bw);
    k_cosfull<<<dim3(B * L, 6), 256, 0, stream>>>(q1, q2, mean_fw, mean_bw,
                                                  maxat_fw, maxat_bw, W, out);
    k_maxpool_mfma<<<dim3(B * 2, P), 256, 0, stream>>>(q1, q2, W, out);
}

// Round 7
// 128.704 us; speedup vs baseline: 4.5325x; 1.2623x over previous
//
#include <hip/hip_runtime.h>
#include <hip/hip_bf16.h>

#define B 16
#define L 128
#define H 256
#define H2 512
#define P 16
#define EPSF 1e-8f
#define LDSTR 72   // shorts per LDS row: 64 + 8 pad -> 144 B (2-way bank alias = free)

typedef __attribute__((ext_vector_type(8))) short short8;
typedef __attribute__((ext_vector_type(4))) short short4v;
typedef __attribute__((ext_vector_type(4))) float f32x4;

__device__ __forceinline__ short f2bf(float x) {
    unsigned u = __builtin_bit_cast(unsigned, x);
    u += 0x7fffu + ((u >> 16) & 1u);   // RNE; inputs finite
    return (short)(u >> 16);
}
__device__ __forceinline__ float bf2f(short s) {
    unsigned u = ((unsigned)(unsigned short)s) << 16;
    return __builtin_bit_cast(float, u);
}

// ---- K1: attention via bf16 MFMA + exact fp32 norms ------------------------
__global__ void __launch_bounds__(256) k_att_mfma(
        const float* __restrict__ q1, const float* __restrict__ q2,
        float* __restrict__ att_fw, float* __restrict__ att_bw,
        float* __restrict__ attsum) {
    int bd = blockIdx.x;
    int b = bd >> 1, dir = bd & 1;
    int m0 = blockIdx.y * 16;
    int t = threadIdx.x;

    __shared__ short As[16 * LDSTR];
    __shared__ short Bs[128 * LDSTR];
    __shared__ float nA[16], nB[L];
    __shared__ float part[4][16];

    f32x4 acc[2];
    acc[0] = (f32x4){0.f, 0.f, 0.f, 0.f};
    acc[1] = (f32x4){0.f, 0.f, 0.f, 0.f};

    int wave = t >> 6;
    int l = t & 63;
    int q = l >> 4;
    int coll = l & 15;
    int n0 = wave * 32;

    int arow = t >> 4;
    int acol = (t & 15) * 4;
    int brow = t >> 1;
    int bcol0 = (t & 1) * 32;

    const float* q1b = q1 + ((size_t)b * L + m0) * H2 + dir * H;
    const float* q2b = q2 + ((size_t)b * L) * H2 + dir * H;

    float normA = 0.f, normB = 0.f;

    for (int kt = 0; kt < 4; kt++) {
        int k0 = kt * 64;
        {
            float4 va = *(const float4*)(q1b + (size_t)arow * H2 + k0 + acol);
            normA += va.x * va.x + va.y * va.y + va.z * va.z + va.w * va.w;
            short4v sa = { f2bf(va.x), f2bf(va.y), f2bf(va.z), f2bf(va.w) };
            *(short4v*)(As + arow * LDSTR + acol) = sa;
        }
        for (int cc = 0; cc < 8; cc++) {
            float4 vb = *(const float4*)(q2b + (size_t)brow * H2 + k0 + bcol0 + cc * 4);
            normB += vb.x * vb.x + vb.y * vb.y + vb.z * vb.z + vb.w * vb.w;
            short4v sb = { f2bf(vb.x), f2bf(vb.y), f2bf(vb.z), f2bf(vb.w) };
            *(short4v*)(Bs + brow * LDSTR + bcol0 + cc * 4) = sb;
        }
        __syncthreads();
        for (int ks = 0; ks < 2; ks++) {
            int koff = ks * 32 + q * 8;
            short8 af = *(const short8*)(As + coll * LDSTR + koff);
            short8 bf0 = *(const short8*)(Bs + (n0 + coll) * LDSTR + koff);
            short8 bf1 = *(const short8*)(Bs + (n0 + 16 + coll) * LDSTR + koff);
            acc[0] = __builtin_amdgcn_mfma_f32_16x16x32_bf16(af, bf0, acc[0], 0, 0, 0);
            acc[1] = __builtin_amdgcn_mfma_f32_16x16x32_bf16(af, bf1, acc[1], 0, 0, 0);
        }
        __syncthreads();
    }
    {
        float sA = normA;
        for (int off = 1; off < 16; off <<= 1) sA += __shfl_xor(sA, off, 16);
        if ((t & 15) == 0) nA[arow] = sqrtf(sA);
        float sB = normB + __shfl_xor(normB, 1, 2);
        if ((t & 1) == 0) nB[brow] = sqrtf(sB);
    }
    __syncthreads();

    float* attout = dir ? att_bw : att_fw;
    size_t bL = (size_t)b * L;
    float n1v[4];
    for (int r = 0; r < 4; r++) n1v[r] = nA[q * 4 + r];
    float rsum[4] = {0.f, 0.f, 0.f, 0.f};
    for (int nt = 0; nt < 2; nt++) {
        int col = n0 + nt * 16 + coll;
        float n2v = nB[col];
        for (int r = 0; r < 4; r++) {
            int row = m0 + q * 4 + r;
            float den = n1v[r] * n2v;
            den = den > EPSF ? den : EPSF;
            float a = acc[nt][r] / den;
            attout[(bL + row) * L + col] = a;
            rsum[r] += a;
        }
    }
    if (dir == 0) {
        for (int off = 1; off < 16; off <<= 1)
            for (int r = 0; r < 4; r++)
                rsum[r] += __shfl_xor(rsum[r], off, 16);
        if (coll == 0)
            for (int r = 0; r < 4; r++)
                part[wave][q * 4 + r] = rsum[r];
        __syncthreads();
        if (t < 16)
            attsum[bL + m0 + t] = part[0][t] + part[1][t] + part[2][t] + part[3][t];
    }
}

// ---- K2: weighted mean (bw uses fw row-sum, per reference) + max of att*q2 --
// Grid (B*2, 16): block = (b, dir, 8 i-rows). 4 waves split j; lanes own
// float4 h-chunks. Cross-wave sum/max reduce via LDS, 2 rows per round.
__global__ void __launch_bounds__(256) k_meanmax_v2(
        const float* __restrict__ q2,
        const float* __restrict__ att_fw, const float* __restrict__ att_bw,
        const float* __restrict__ attsum,
        float* __restrict__ mean_fw, float* __restrict__ mean_bw,
        float* __restrict__ maxat_fw, float* __restrict__ maxat_bw) {
    int bd = blockIdx.x;
    int b = bd >> 1, dir = bd & 1;
    int i0 = blockIdx.y * 8;
    int t = threadIdx.x;
    int wave = t >> 6, l = t & 63;

    __shared__ float at[8][L];
    __shared__ float Ss[8];
    __shared__ f32x4 red[4][64][4];   // [wave][lane][{sum,max}x2rows] = 16 KB

    const float* att = dir ? att_bw : att_fw;
    for (int v = t; v < 8 * L; v += 256) {
        int r = v >> 7, j = v & 127;
        at[r][j] = att[((size_t)b * L + i0 + r) * L + j];
    }
    if (t < 8) {
        float s = attsum[(size_t)b * L + i0 + t];
        Ss[t] = s > EPSF ? s : EPSF;
    }
    __syncthreads();

    f32x4 sum[8], mx[8];
    for (int r = 0; r < 8; r++) {
        sum[r] = (f32x4){0.f, 0.f, 0.f, 0.f};
        mx[r] = (f32x4){-INFINITY, -INFINITY, -INFINITY, -INFINITY};
    }

    const float* q2b = q2 + (size_t)b * L * H2 + dir * H;
    for (int jj = 0; jj < 32; jj++) {
        int j = wave * 32 + jj;
        float4 c = *(const float4*)(q2b + (size_t)j * H2 + l * 4);
        for (int r = 0; r < 8; r++) {
            float w = at[r][j];
            f32x4 v = { w * c.x, w * c.y, w * c.z, w * c.w };
            sum[r] += v;
            mx[r][0] = fmaxf(mx[r][0], v[0]);
            mx[r][1] = fmaxf(mx[r][1], v[1]);
            mx[r][2] = fmaxf(mx[r][2], v[2]);
            mx[r][3] = fmaxf(mx[r][3], v[3]);
        }
    }

    float* meanout = dir ? mean_bw : mean_fw;
    float* maxout = dir ? maxat_bw : maxat_fw;
    for (int rr = 0; rr < 4; rr++) {
        __syncthreads();
        red[wave][l][0] = sum[rr * 2];
        red[wave][l][1] = mx[rr * 2];
        red[wave][l][2] = sum[rr * 2 + 1];
        red[wave][l][3] = mx[rr * 2 + 1];
        __syncthreads();
        if (t < 128) {
            int r2 = t >> 6;
            int lane = t & 63;
            f32x4 s = red[0][lane][r2 * 2];
            f32x4 m = red[0][lane][r2 * 2 + 1];
            for (int w = 1; w < 4; w++) {
                s += red[w][lane][r2 * 2];
                f32x4 m2 = red[w][lane][r2 * 2 + 1];
                m[0] = fmaxf(m[0], m2[0]);
                m[1] = fmaxf(m[1], m2[1]);
                m[2] = fmaxf(m[2], m2[2]);
                m[3] = fmaxf(m[3], m2[3]);
            }
            int row = i0 + rr * 2 + r2;
            float inv = 1.f / Ss[rr * 2 + r2];
            size_t o = ((size_t)b * L + row) * H + lane * 4;
            *(f32x4*)(meanout + o) = s * inv;
            *(f32x4*)(maxout + o) = m;
        }
    }
}

// ---- K3: six cos_full pieces ------------------------------------------------
__global__ void __launch_bounds__(256) k_cosfull(
        const float* __restrict__ q1, const float* __restrict__ q2,
        const float* __restrict__ mean_fw, const float* __restrict__ mean_bw,
        const float* __restrict__ maxat_fw, const float* __restrict__ maxat_bw,
        const float* __restrict__ W, float* __restrict__ out) {
    int blk = blockIdx.x;          // b*L + i
    int piece = blockIdx.y;        // 0..5
    int b = blk / L;
    int t = threadIdx.x;
    int p = t >> 4, l = t & 15;    // 16 perspectives x 16 lanes

    int widx, col, dir;
    const float* vptr;
    switch (piece) {
        case 0: widx = 0; col = 0;   dir = 0; vptr = q2 + ((size_t)b * L + (L - 1)) * H2;  break;
        case 1: widx = 1; col = 16;  dir = 1; vptr = q2 + ((size_t)b * L) * H2 + H;        break;
        case 2: widx = 4; col = 64;  dir = 0; vptr = mean_fw + (size_t)blk * H;            break;
        case 3: widx = 5; col = 80;  dir = 1; vptr = mean_bw + (size_t)blk * H;            break;
        case 4: widx = 6; col = 96;  dir = 0; vptr = maxat_fw + (size_t)blk * H;           break;
        default: widx = 7; col = 112; dir = 1; vptr = maxat_bw + (size_t)blk * H;          break;
    }
    const float* r1 = q1 + (size_t)blk * H2 + dir * H;
    const float* wrow = W + ((size_t)widx * P + p) * H;
    float num = 0, na = 0, nc = 0;
    for (int k = 0; k < 16; k++) {
        int h = l + 16 * k;
        float wv = wrow[h];
        float ws = wv * wv;
        float a = r1[h];
        float c = vptr[h];
        num += a * c * ws;
        na  += a * a * ws;
        nc  += c * c * ws;
    }
    for (int off = 8; off; off >>= 1) {
        num += __shfl_down(num, off, 16);
        na  += __shfl_down(na,  off, 16);
        nc  += __shfl_down(nc,  off, 16);
    }
    if (l == 0) {
        float den = sqrtf(na) * sqrtf(nc);
        den = den > EPSF ? den : EPSF;
        out[(size_t)blk * 128 + col + p] = num / den;
    }
}

// ---- K4: cos_maxpool via bf16 MFMA ------------------------------------------
__global__ void __launch_bounds__(256, 2) k_maxpool_mfma(
        const float* __restrict__ q1, const float* __restrict__ q2,
        const float* __restrict__ W, float* __restrict__ out) {
    int bd = blockIdx.x;          // b*2 + dir
    int b = bd >> 1, dir = bd & 1;
    int p = blockIdx.y;
    int t = threadIdx.x;

    __shared__ short As[128 * LDSTR];
    __shared__ short Bs[128 * LDSTR];
    __shared__ float wv[H];
    __shared__ float nrm[256];    // [0..127]=||a_i||, [128..255]=||c_j||

    wv[t] = W[((size_t)(2 + dir) * P + p) * H + t];
    __syncthreads();

    f32x4 acc[2][8];
    for (int mt = 0; mt < 2; mt++)
        for (int nt = 0; nt < 8; nt++)
            acc[mt][nt] = (f32x4){0.f, 0.f, 0.f, 0.f};

    int lane16 = t & 15;
    int rgrp = t >> 4;
    int nrow = t & 127;
    int nmat = t >> 7;
    float normacc = 0.f;

    int wave = t >> 6;
    int l = t & 63;
    int q = l >> 4;
    int coll = l & 15;
    int m0 = wave * 32;

    const float* q1b = q1 + ((size_t)b * L) * H2 + dir * H;
    const float* q2b = q2 + ((size_t)b * L) * H2 + dir * H;

    for (int kt = 0; kt < 4; kt++) {
        int k0 = kt * 64;
        for (int pass = 0; pass < 8; pass++) {
            int row = rgrp + pass * 16;
            int c4 = lane16 * 4;
            float w0 = wv[k0 + c4], w1 = wv[k0 + c4 + 1];
            float w2 = wv[k0 + c4 + 2], w3 = wv[k0 + c4 + 3];
            float4 va = *(const float4*)(q1b + (size_t)row * H2 + k0 + c4);
            short4v sa = { f2bf(va.x * w0), f2bf(va.y * w1), f2bf(va.z * w2), f2bf(va.w * w3) };
            *(short4v*)(As + row * LDSTR + c4) = sa;
            float4 vb = *(const float4*)(q2b + (size_t)row * H2 + k0 + c4);
            short4v sb = { f2bf(vb.x * w0), f2bf(vb.y * w1), f2bf(vb.z * w2), f2bf(vb.w * w3) };
            *(short4v*)(Bs + row * LDSTR + c4) = sb;
        }
        __syncthreads();
        {
            const short* rowp = (nmat ? Bs : As) + nrow * LDSTR;
            for (int c = 0; c < 8; c++) {
                short8 s = *(const short8*)(rowp + c * 8);
                for (int jj = 0; jj < 8; jj++) {
                    float f = bf2f(s[jj]);
                    normacc += f * f;
                }
            }
        }
        for (int ks = 0; ks < 2; ks++) {
            int koff = ks * 32 + q * 8;
            short8 af0 = *(const short8*)(As + (m0 + coll) * LDSTR + koff);
            short8 af1 = *(const short8*)(As + (m0 + 16 + coll) * LDSTR + koff);
            for (int nt = 0; nt < 8; nt++) {
                short8 bfr = *(const short8*)(Bs + (nt * 16 + coll) * LDSTR + koff);
                acc[0][nt] = __builtin_amdgcn_mfma_f32_16x16x32_bf16(af0, bfr, acc[0][nt], 0, 0, 0);
                acc[1][nt] = __builtin_amdgcn_mfma_f32_16x16x32_bf16(af1, bfr, acc[1][nt], 0, 0, 0);
            }
        }
        __syncthreads();
    }
    nrm[t] = sqrtf(normacc);
    __syncthreads();

    float nav[2][4];
    for (int mt = 0; mt < 2; mt++)
        for (int r = 0; r < 4; r++)
            nav[mt][r] = nrm[m0 + mt * 16 + q * 4 + r];
    float rmax[2][4];
    for (int mt = 0; mt < 2; mt++)
        for (int r = 0; r < 4; r++) rmax[mt][r] = -INFINITY;
    for (int nt = 0; nt < 8; nt++) {
        float ncv = nrm[128 + nt * 16 + coll];
        for (int mt = 0; mt < 2; mt++)
            for (int r = 0; r < 4; r++) {
                float den = fmaxf(nav[mt][r] * ncv, EPSF);
                float v = acc[mt][nt][r] / den;
                rmax[mt][r] = fmaxf(rmax[mt][r], v);
            }
    }
    for (int off = 1; off < 16; off <<= 1)
        for (int mt = 0; mt < 2; mt++)
            for (int r = 0; r < 4; r++)
                rmax[mt][r] = fmaxf(rmax[mt][r], __shfl_xor(rmax[mt][r], off, 16));
    if (coll == 0) {
        for (int mt = 0; mt < 2; mt++)
            for (int r = 0; r < 4; r++) {
                int row = m0 + mt * 16 + q * 4 + r;
                out[((size_t)b * L + row) * 128 + 32 + dir * 16 + p] = rmax[mt][r];
            }
    }
}

extern "C" void kernel_launch(void* const* d_in, const int* in_sizes, int n_in,
                              void* d_out, int out_size, void* d_ws, size_t ws_size,
                              hipStream_t stream) {
    const float* q1 = (const float*)d_in[0];
    const float* q2 = (const float*)d_in[1];
    const float* W  = (const float*)d_in[2];
    float* out = (float*)d_out;

    float* ws = (float*)d_ws;
    float* attsum = ws;                               // B*L
    float* att_fw = attsum + B * L;                   // B*L*L
    float* att_bw = att_fw + (size_t)B * L * L;
    float* mean_fw = att_bw + (size_t)B * L * L;      // B*L*H each below
    float* mean_bw = mean_fw + (size_t)B * L * H;
    float* maxat_fw = mean_bw + (size_t)B * L * H;
    float* maxat_bw = maxat_fw + (size_t)B * L * H;

    k_att_mfma<<<dim3(B * 2, 8), 256, 0, stream>>>(q1, q2, att_fw, att_bw, attsum);
    k_meanmax_v2<<<dim3(B * 2, 16), 256, 0, stream>>>(q2, att_fw, att_bw, attsum,
                                                      mean_fw, mean_bw, maxat_fw, maxat_bw);
    k_cosfull<<<dim3(B * L, 6), 256, 0, stream>>>(q1, q2, mean_fw, mean_bw,
                                                  maxat_fw, maxat_bw, W, out);
    k_maxpool_mfma<<<dim3(B * 2, P), 256, 0, stream>>>(q1, q2, W, out);
}